// Round 7
// baseline (703.057 us; speedup 1.0000x reference)
//
#include <hip/hip_runtime.h>
#include <hip/hip_bf16.h>
#include <stdint.h>

// ---------------------------------------------------------------------------
// Bahdanau additive attention, B=32, T=2048, D=U=1024. fp32 in/out.
// Outputs (fp32, flat): ctx [32*1024] then weights [32*2048].
// Round 10 (resubmit x3; r4/r5/r6 benches never ran): 3-dispatch pipeline,
// workspace at the r1-verified 133.25 MB footprint (ctx_part aliases W2T;
// cnt in the old w_f slot).
//   k_prep      : W2 transpose->bf16 | qproj v2 | values fp32->bf16 | cnt=0
//   k_score_gemm: both operands bf16 via global_load_lds DMA (r1-verified,
//                 200us, 0 bank conflicts)
//   k_smax_ctx  : fused softmax + weighted-sum + last-block ctx reduce
// ---------------------------------------------------------------------------

typedef unsigned short ushort_t;
typedef short bf16x8 __attribute__((ext_vector_type(8)));
typedef float f32x4 __attribute__((ext_vector_type(4)));

#define GLOBAL_AS __attribute__((address_space(1)))
#define LDS_AS    __attribute__((address_space(3)))

__device__ __forceinline__ ushort_t f2bf(float f) {
    union { float f; unsigned int u; } v;
    v.f = f;
    unsigned int u = v.u;
    unsigned int r = u + 0x7FFFu + ((u >> 16) & 1u);  // RNE
    return (ushort_t)(r >> 16);
}
__device__ __forceinline__ unsigned int pk2(float a, float b) {
    union { __hip_bfloat162 h; unsigned int u; } c;
    c.h = __float22bfloat162_rn(make_float2(a, b));  // v_cvt_pk_bf16_f32
    return c.u;
}
__device__ __forceinline__ float fast_tanh(float x) {
    float ax = __builtin_fabsf(x);
    float e = __expf(-2.0f * ax);
    float t = (1.0f - e) * __builtin_amdgcn_rcpf(1.0f + e);
    return __builtin_copysignf(t, x);
}

static constexpr int B_ = 32, T_ = 2048, D_ = 1024, U_ = 1024;
static constexpr int M_ = B_ * T_;  // 65536
static constexpr int TRANS_B = 1024;
static constexpr int QPROJ_B = 64;   // (4 batch-groups of 8) x (16 u-chunks of 64)
static constexpr int CONV_B  = 4096; // values convert blocks

// -------- kernel 1: fused prep (transpose | qproj | convert | cnt=0) -------
__global__ __launch_bounds__(256) void k_prep(const float* __restrict__ W2,
                                              const float* __restrict__ query,
                                              const float* __restrict__ W1,
                                              const float* __restrict__ b1,
                                              const float* __restrict__ b2,
                                              const float* __restrict__ values,
                                              ushort_t* __restrict__ W2T,
                                              float* __restrict__ qpb,
                                              ushort_t* __restrict__ vb,
                                              unsigned int* __restrict__ cnt) {
    __shared__ float smem[8192 + 4 * 64 * 9];  // qs[8][1024] | red[4][64][9(pad)]
    int bid = blockIdx.x;
    const int tid = threadIdx.x;

    if (bid < TRANS_B) {  // W2 [D][U] -> W2T [U][D] bf16
        if (bid == 0 && tid < B_) cnt[tid] = 0u;  // reset reduce counters
        float(*tile)[33] = (float(*)[33])smem;
        int u0 = (bid & 31) * 32, d0 = (bid >> 5) * 32;
        int tx = tid & 31, ty = tid >> 5;
#pragma unroll
        for (int r = 0; r < 4; ++r)
            tile[ty + r * 8][tx] = W2[(size_t)(d0 + ty + r * 8) * U_ + (u0 + tx)];
        __syncthreads();
#pragma unroll
        for (int r = 0; r < 4; ++r)
            W2T[(size_t)(u0 + ty + r * 8) * D_ + (d0 + tx)] = f2bf(tile[tx][ty + r * 8]);
        return;
    }
    bid -= TRANS_B;

    if (bid >= QPROJ_B) {  // values fp32 -> bf16
        const int cb = bid - QPROJ_B;  // 0..CONV_B-1
        const size_t base = (size_t)cb * 2048 + tid;
#pragma unroll
        for (int k = 0; k < 8; ++k) {
            const size_t chunk = base + (size_t)k * 256;  // 8 floats per chunk
            const float* s = values + chunk * 8;
            f32x4 v0 = *(const f32x4*)s;
            f32x4 v1 = *(const f32x4*)(s + 4);
            uint4 p;
            p.x = pk2(v0[0], v0[1]);
            p.y = pk2(v0[2], v0[3]);
            p.z = pk2(v1[0], v1[1]);
            p.w = pk2(v1[2], v1[3]);
            *(uint4*)(vb + chunk * 8) = p;
        }
        return;
    }

    // qproj: qpb[b][u] = query[b]@W1[:,u] + b1[u] + b2[u]  (8 batches/block)
    const int bg = bid >> 4;  // batch group of 8
    const int uc = bid & 15;  // 64-u chunk

    float* qs = smem;  // [8][1024]
    float(*red)[64][9] = (float(*)[64][9])(smem + 8192);

    for (int i = tid; i < 8 * 1024; i += 256)
        qs[i] = query[(size_t)(bg * 8 + (i >> 10)) * D_ + (i & 1023)];
    __syncthreads();

    const int ul = tid & 63, ds = tid >> 6;
    const int u = uc * 64 + ul;
    float acc[8] = {0.f, 0.f, 0.f, 0.f, 0.f, 0.f, 0.f, 0.f};
#pragma unroll 8
    for (int d = ds * 256; d < ds * 256 + 256; ++d) {
        const float w = W1[(size_t)d * U_ + u];
#pragma unroll
        for (int b = 0; b < 8; ++b) acc[b] += qs[(b << 10) + d] * w;  // LDS broadcast
    }
#pragma unroll
    for (int b = 0; b < 8; ++b) red[ds][ul][b] = acc[b];
    __syncthreads();
    for (int i = tid; i < 512; i += 256) {
        const int b = i & 7, uu = i >> 3;
        const float s = (red[0][uu][b] + red[1][uu][b]) + (red[2][uu][b] + red[3][uu][b]);
        const int ug = uc * 64 + uu;
        qpb[(size_t)(bg * 8 + b) * U_ + ug] = s + b1[ug] + b2[ug];
    }
}

// ---------------- kernel 2: fused GEMM + tanh + Wv-dot ---------------------
// Both tiles staged via global_load_lds DMA from bf16 sources, XOR-swizzled
// at 16B chunks: LDS position p of row r holds source chunk p ^ (r&7).
#define BM 128
#define BN 128
#define BK 64

__global__ __launch_bounds__(256) void k_score_gemm(const ushort_t* __restrict__ vb,
                                                    const ushort_t* __restrict__ W2T,
                                                    const float* __restrict__ qpb,
                                                    const float* __restrict__ Wv,
                                                    float* __restrict__ scores_partial) {
    __shared__ ushort_t As[BM * BK];  // 16 KB
    __shared__ ushort_t Bs[BN * BK];  // 16 KB
    __shared__ float sScore[BM];

    const int tid = threadIdx.x;
    const int lane = tid & 63;
    const int w = tid >> 6;
    const int wm = w >> 1, wn = w & 1;

    // XCD-grouped order: the 8 n-blocks of an m-tile get adjacent block ids
    const int g = blockIdx.x;
    const int mt = ((g >> 6) << 3) | (g & 7);
    const int nt = (g >> 3) & 7;
    const int m0 = mt * BM, n0 = nt * BN;

    if (tid < BM) sScore[tid] = 0.f;

    f32x4 acc[4][4];
#pragma unroll
    for (int i = 0; i < 4; ++i)
#pragma unroll
        for (int j = 0; j < 4; ++j) acc[i][j] = (f32x4){0.f, 0.f, 0.f, 0.f};

    // ---- DMA staging map: wave w, rows w*8+lr+i*32, source-side swizzle
    const int lr = lane >> 3;
    const int cS = (lane & 7) ^ lr;  // pre-swizzled source chunk
    const ushort_t* bBase = W2T + (size_t)(n0 + w * 8 + lr) * D_ + cS * 8;
    const ushort_t* aBase = vb + (size_t)(m0 + w * 8 + lr) * D_ + cS * 8;

    const int quad = lane >> 4;
    const int l15 = lane & 15;
    const int l7 = l15 & 7;

    for (int k0 = 0; k0 < D_; k0 += BK) {
#pragma unroll
        for (int i = 0; i < 4; ++i) {
            __builtin_amdgcn_global_load_lds(
                (const GLOBAL_AS void*)(bBase + k0 + (size_t)i * 32 * D_),
                (LDS_AS void*)(Bs + i * 2048 + w * 512), 16, 0, 0);
        }
#pragma unroll
        for (int i = 0; i < 4; ++i) {
            __builtin_amdgcn_global_load_lds(
                (const GLOBAL_AS void*)(aBase + k0 + (size_t)i * 32 * D_),
                (LDS_AS void*)(As + i * 2048 + w * 512), 16, 0, 0);
        }
        __syncthreads();
#pragma unroll
        for (int kk = 0; kk < BK; kk += 32) {
            bf16x8 af[4], bfr[4];
            const int cb = kk >> 3;  // 0 or 4
#pragma unroll
            for (int i = 0; i < 4; ++i) {
                int r = wm * 64 + i * 16 + l15;
                af[i] = *(const bf16x8*)(As + (r << 6) + (((quad + cb) ^ l7) << 3));
            }
#pragma unroll
            for (int j = 0; j < 4; ++j) {
                int r = wn * 64 + j * 16 + l15;
                bfr[j] = *(const bf16x8*)(Bs + (r << 6) + (((quad + cb) ^ l7) << 3));
            }
#pragma unroll
            for (int i = 0; i < 4; ++i)
#pragma unroll
                for (int j = 0; j < 4; ++j)
                    acc[i][j] = __builtin_amdgcn_mfma_f32_16x16x32_bf16(
                        af[i], bfr[j], acc[i][j], 0, 0, 0);
        }
        __syncthreads();
    }

    // epilogue: C row = wm*64+i*16+quad*4+r, col(u) = n0+wn*64+j*16+l15
    const int b = m0 >> 11;
    const float* qp = qpb + b * U_;
    float qv[4], wv[4];
#pragma unroll
    for (int j = 0; j < 4; ++j) {
        int u = n0 + wn * 64 + j * 16 + l15;
        qv[j] = qp[u];
        wv[j] = Wv[u];
    }
#pragma unroll
    for (int i = 0; i < 4; ++i) {
#pragma unroll
        for (int r = 0; r < 4; ++r) {
            float s = 0.f;
#pragma unroll
            for (int j = 0; j < 4; ++j) s += fast_tanh(acc[i][j][r] + qv[j]) * wv[j];
            s += __shfl_xor(s, 1);
            s += __shfl_xor(s, 2);
            s += __shfl_xor(s, 4);
            s += __shfl_xor(s, 8);
            if (l15 == 0) atomicAdd(&sScore[wm * 64 + i * 16 + quad * 4 + r], s);
        }
    }
    __syncthreads();
    if (tid < BM) scores_partial[(size_t)(m0 + tid) * 8 + nt] = sScore[tid];
}

// ------- kernel 3: fused softmax + weighted sum + last-block reduce --------
__global__ __launch_bounds__(256) void k_smax_ctx(const float* __restrict__ scores_partial,
                                                  const float* __restrict__ bv,
                                                  const float* __restrict__ values,
                                                  float* __restrict__ ctx_part,
                                                  unsigned int* __restrict__ cnt,
                                                  float* __restrict__ out_w,
                                                  float* __restrict__ out_ctx) {
    const int tc = blockIdx.x;  // 0..15
    const int b = blockIdx.y;   // 0..31
    const int tid = threadIdx.x;
    __shared__ float s[T_];  // 8 KB
    __shared__ float red[4];
    __shared__ float wls[128];
    __shared__ unsigned int is_last;
    const float bvf = bv[0];

    // softmax normalizer over full T (redundant per tc; partials are L2-hot)
    float lmax = -1e30f;
    for (int t = tid; t < T_; t += 256) {
        const float* p = scores_partial + (size_t)(b * T_ + t) * 8;
        float sc = ((p[0] + p[1]) + (p[2] + p[3])) + ((p[4] + p[5]) + (p[6] + p[7])) + bvf;
        s[t] = sc;
        lmax = fmaxf(lmax, sc);
    }
    for (int off = 32; off; off >>= 1) lmax = fmaxf(lmax, __shfl_xor(lmax, off));
    if ((tid & 63) == 0) red[tid >> 6] = lmax;
    __syncthreads();
    const float gmax = fmaxf(fmaxf(red[0], red[1]), fmaxf(red[2], red[3]));

    float lsum = 0.f;
    for (int t = tid; t < T_; t += 256) {
        float e = __expf(s[t] - gmax);
        s[t] = e;
        lsum += e;
    }
    for (int off = 32; off; off >>= 1) lsum += __shfl_xor(lsum, off);
    __syncthreads();
    if ((tid & 63) == 0) red[tid >> 6] = lsum;
    __syncthreads();
    const float ginv = 1.f / ((red[0] + red[1]) + (red[2] + red[3]));

    // our 128-row slice: weights -> out_w + LDS
    if (tid < 128) {
        float wgt = s[tc * 128 + tid] * ginv;
        wls[tid] = wgt;
        out_w[b * T_ + tc * 128 + tid] = wgt;
    }
    __syncthreads();

    // weighted sum over our 128 rows
    f32x4 acc = (f32x4){0.f, 0.f, 0.f, 0.f};
    const float* base = values + (size_t)(b * T_ + tc * 128) * D_ + tid * 4;
#pragma unroll 4
    for (int tt = 0; tt < 128; ++tt)
        acc += wls[tt] * *(const f32x4*)(base + (size_t)tt * D_);
    *(f32x4*)(ctx_part + ((size_t)(tc * 32 + b) << 10) + tid * 4) = acc;

    // last block per batch reduces the 16 partials
    __threadfence();
    if (tid == 0) is_last = (atomicAdd(&cnt[b], 1u) == 15u) ? 1u : 0u;
    __syncthreads();
    if (is_last) {
        __threadfence();  // acquire side
        f32x4 ssum = (f32x4){0.f, 0.f, 0.f, 0.f};
#pragma unroll
        for (int q = 0; q < 16; ++q)
            ssum += *(const f32x4*)(ctx_part + ((size_t)(q * 32 + b) << 10) + tid * 4);
        *(f32x4*)(out_ctx + b * D_ + tid * 4) = ssum;
        if (tid == 0) cnt[b] = 0u;  // self-clean for next iteration
    }
}

// ---------------------------------------------------------------------------
extern "C" void kernel_launch(void* const* d_in, const int* in_sizes, int n_in,
                              void* d_out, int out_size, void* d_ws, size_t ws_size,
                              hipStream_t stream) {
    const float* query  = (const float*)d_in[0];
    const float* values = (const float*)d_in[1];
    const float* W1     = (const float*)d_in[2];
    const float* b1     = (const float*)d_in[3];
    const float* W2     = (const float*)d_in[4];
    const float* b2     = (const float*)d_in[5];
    const float* Wv     = (const float*)d_in[6];
    const float* bv     = (const float*)d_in[7];

    float* out_ctx = (float*)d_out;          // [32*1024]
    float* out_w   = out_ctx + B_ * D_;      // [32*2048]

    char* ws = (char*)d_ws;
    // Footprint 0x500000 + 128 MB = 133.25 MB, exactly the r1-verified bound.
    // ctx_part ALIASES W2T (offset 0): W2T is dead after k_score_gemm and
    // rewritten fresh by k_prep each iteration; ctx_part lives only within
    // k_smax_ctx. cnt sits in the old w_f slot (unused in this design).
    const size_t OFF_W2T = 0;                 // 2 MB bf16  (later: ctx_part 2 MB)
    const size_t OFF_QPB = 0x200000;          // 128 KB
    const size_t OFF_SP  = 0x220000;          // 2 MB
    const size_t OFF_CNT = 0x420000;          // 128 B counters
    const size_t OFF_VB  = 0x500000;          // 128 MB bf16 values

    ushort_t*     W2T            = (ushort_t*)(ws + OFF_W2T);
    float*        ctx_part       = (float*)(ws + OFF_W2T);   // alias, see above
    float*        qpb            = (float*)(ws + OFF_QPB);
    float*        scores_partial = (float*)(ws + OFF_SP);
    unsigned int* cnt            = (unsigned int*)(ws + OFF_CNT);
    ushort_t*     vb             = (ushort_t*)(ws + OFF_VB);

    k_prep<<<dim3(TRANS_B + QPROJ_B + CONV_B), 256, 0, stream>>>(
        W2, query, W1, b1, b2, values, W2T, qpb, vb, cnt);
    k_score_gemm<<<dim3((M_ / BM) * (U_ / BN)), 256, 0, stream>>>(
        vb, W2T, qpb, Wv, scores_partial);
    k_smax_ctx<<<dim3(16, B_), 256, 0, stream>>>(
        scores_partial, bv, values, ctx_part, cnt, out_w, out_ctx);

    (void)in_sizes; (void)n_in; (void)out_size; (void)ws_size;
}

// Round 9
// 628.501 us; speedup vs baseline: 1.1186x; 1.1186x over previous
//
#include <hip/hip_runtime.h>
#include <hip/hip_bf16.h>
#include <stdint.h>

// ---------------------------------------------------------------------------
// Bahdanau additive attention, B=32, T=2048, D=U=1024. fp32 in/out.
// Outputs (fp32, flat): ctx [32*1024] then weights [32*2048].
// Round 11 (resubmit; r8 bench never ran): revert r7's fused-tail regression
// (threadfence election cost +76us). 5 dispatches, no atomics/memset/fence:
//   k_prep      : [qproj v2 | values fp32->bf16 | W2 transpose] -- qproj
//                 blocks FIRST so the 64 long-running blocks start early
//                 (straggler overlaps the 61us convert).
//   k_score_gemm: bf16 dual global_load_lds DMA (verified 200-205us x2)
//   k_softmax   : 1 block/batch, writes out_w
//   k_ctx       : (32,32) grid, 64 rows/block -> 4 MB partials
//   k_ctx_fin   : reduce 32 partials -> out_ctx
// ---------------------------------------------------------------------------

typedef unsigned short ushort_t;
typedef short bf16x8 __attribute__((ext_vector_type(8)));
typedef float f32x4 __attribute__((ext_vector_type(4)));

#define GLOBAL_AS __attribute__((address_space(1)))
#define LDS_AS    __attribute__((address_space(3)))

__device__ __forceinline__ ushort_t f2bf(float f) {
    union { float f; unsigned int u; } v;
    v.f = f;
    unsigned int u = v.u;
    unsigned int r = u + 0x7FFFu + ((u >> 16) & 1u);  // RNE
    return (ushort_t)(r >> 16);
}
__device__ __forceinline__ unsigned int pk2(float a, float b) {
    union { __hip_bfloat162 h; unsigned int u; } c;
    c.h = __float22bfloat162_rn(make_float2(a, b));  // v_cvt_pk_bf16_f32
    return c.u;
}
__device__ __forceinline__ float fast_tanh(float x) {
    float ax = __builtin_fabsf(x);
    float e = __expf(-2.0f * ax);
    float t = (1.0f - e) * __builtin_amdgcn_rcpf(1.0f + e);
    return __builtin_copysignf(t, x);
}

static constexpr int B_ = 32, T_ = 2048, D_ = 1024, U_ = 1024;
static constexpr int M_ = B_ * T_;  // 65536
static constexpr int QPROJ_B = 64;   // (4 batch-groups of 8) x (16 u-chunks of 64)
static constexpr int CONV_B  = 4096; // values convert blocks
static constexpr int TRANS_B = 1024;

// ------ kernel 1: fused prep (qproj FIRST | convert | transpose LAST) ------
__global__ __launch_bounds__(256) void k_prep(const float* __restrict__ W2,
                                              const float* __restrict__ query,
                                              const float* __restrict__ W1,
                                              const float* __restrict__ b1,
                                              const float* __restrict__ b2,
                                              const float* __restrict__ values,
                                              ushort_t* __restrict__ W2T,
                                              float* __restrict__ qpb,
                                              ushort_t* __restrict__ vb) {
    __shared__ float smem[8192 + 4 * 64 * 9];  // qs[8][1024] | red[4][64][9(pad)]
    int bid = blockIdx.x;
    const int tid = threadIdx.x;

    if (bid < QPROJ_B) {
        // qproj: qpb[b][u] = query[b]@W1[:,u] + b1[u] + b2[u]  (8 batches/blk)
        const int bg = bid >> 4;  // batch group of 8
        const int uc = bid & 15;  // 64-u chunk

        float* qs = smem;  // [8][1024]
        float(*red)[64][9] = (float(*)[64][9])(smem + 8192);

        for (int i = tid; i < 8 * 1024; i += 256)
            qs[i] = query[(size_t)(bg * 8 + (i >> 10)) * D_ + (i & 1023)];
        __syncthreads();

        const int ul = tid & 63, ds = tid >> 6;
        const int u = uc * 64 + ul;
        float acc[8] = {0.f, 0.f, 0.f, 0.f, 0.f, 0.f, 0.f, 0.f};
#pragma unroll 8
        for (int d = ds * 256; d < ds * 256 + 256; ++d) {
            const float w = W1[(size_t)d * U_ + u];
#pragma unroll
            for (int b = 0; b < 8; ++b) acc[b] += qs[(b << 10) + d] * w;
        }
#pragma unroll
        for (int b = 0; b < 8; ++b) red[ds][ul][b] = acc[b];
        __syncthreads();
        for (int i = tid; i < 512; i += 256) {
            const int b = i & 7, uu = i >> 3;
            const float s =
                (red[0][uu][b] + red[1][uu][b]) + (red[2][uu][b] + red[3][uu][b]);
            const int ug = uc * 64 + uu;
            qpb[(size_t)(bg * 8 + b) * U_ + ug] = s + b1[ug] + b2[ug];
        }
        return;
    }
    bid -= QPROJ_B;

    if (bid < CONV_B) {  // values fp32 -> bf16
        const size_t base = (size_t)bid * 2048 + tid;
#pragma unroll
        for (int k = 0; k < 8; ++k) {
            const size_t chunk = base + (size_t)k * 256;  // 8 floats per chunk
            const float* s = values + chunk * 8;
            f32x4 v0 = *(const f32x4*)s;
            f32x4 v1 = *(const f32x4*)(s + 4);
            uint4 p;
            p.x = pk2(v0[0], v0[1]);
            p.y = pk2(v0[2], v0[3]);
            p.z = pk2(v1[0], v1[1]);
            p.w = pk2(v1[2], v1[3]);
            *(uint4*)(vb + chunk * 8) = p;
        }
        return;
    }
    bid -= CONV_B;

    // W2 [D][U] -> W2T [U][D] bf16
    {
        float(*tile)[33] = (float(*)[33])smem;
        int u0 = (bid & 31) * 32, d0 = (bid >> 5) * 32;
        int tx = tid & 31, ty = tid >> 5;
#pragma unroll
        for (int r = 0; r < 4; ++r)
            tile[ty + r * 8][tx] = W2[(size_t)(d0 + ty + r * 8) * U_ + (u0 + tx)];
        __syncthreads();
#pragma unroll
        for (int r = 0; r < 4; ++r)
            W2T[(size_t)(u0 + ty + r * 8) * D_ + (d0 + tx)] = f2bf(tile[tx][ty + r * 8]);
    }
}

// ---------------- kernel 2: fused GEMM + tanh + Wv-dot ---------------------
// Both tiles staged via global_load_lds DMA from bf16 sources, XOR-swizzled
// at 16B chunks: LDS position p of row r holds source chunk p ^ (r&7).
#define BM 128
#define BN 128
#define BK 64

__global__ __launch_bounds__(256) void k_score_gemm(const ushort_t* __restrict__ vb,
                                                    const ushort_t* __restrict__ W2T,
                                                    const float* __restrict__ qpb,
                                                    const float* __restrict__ Wv,
                                                    float* __restrict__ scores_partial) {
    __shared__ ushort_t As[BM * BK];  // 16 KB
    __shared__ ushort_t Bs[BN * BK];  // 16 KB
    __shared__ float sScore[BM];

    const int tid = threadIdx.x;
    const int lane = tid & 63;
    const int w = tid >> 6;
    const int wm = w >> 1, wn = w & 1;

    // XCD-grouped order: the 8 n-blocks of an m-tile get adjacent block ids
    const int g = blockIdx.x;
    const int mt = ((g >> 6) << 3) | (g & 7);
    const int nt = (g >> 3) & 7;
    const int m0 = mt * BM, n0 = nt * BN;

    if (tid < BM) sScore[tid] = 0.f;

    f32x4 acc[4][4];
#pragma unroll
    for (int i = 0; i < 4; ++i)
#pragma unroll
        for (int j = 0; j < 4; ++j) acc[i][j] = (f32x4){0.f, 0.f, 0.f, 0.f};

    // ---- DMA staging map: wave w, rows w*8+lr+i*32, source-side swizzle
    const int lr = lane >> 3;
    const int cS = (lane & 7) ^ lr;  // pre-swizzled source chunk
    const ushort_t* bBase = W2T + (size_t)(n0 + w * 8 + lr) * D_ + cS * 8;
    const ushort_t* aBase = vb + (size_t)(m0 + w * 8 + lr) * D_ + cS * 8;

    const int quad = lane >> 4;
    const int l15 = lane & 15;
    const int l7 = l15 & 7;

    for (int k0 = 0; k0 < D_; k0 += BK) {
#pragma unroll
        for (int i = 0; i < 4; ++i) {
            __builtin_amdgcn_global_load_lds(
                (const GLOBAL_AS void*)(bBase + k0 + (size_t)i * 32 * D_),
                (LDS_AS void*)(Bs + i * 2048 + w * 512), 16, 0, 0);
        }
#pragma unroll
        for (int i = 0; i < 4; ++i) {
            __builtin_amdgcn_global_load_lds(
                (const GLOBAL_AS void*)(aBase + k0 + (size_t)i * 32 * D_),
                (LDS_AS void*)(As + i * 2048 + w * 512), 16, 0, 0);
        }
        __syncthreads();
#pragma unroll
        for (int kk = 0; kk < BK; kk += 32) {
            bf16x8 af[4], bfr[4];
            const int cb = kk >> 3;  // 0 or 4
#pragma unroll
            for (int i = 0; i < 4; ++i) {
                int r = wm * 64 + i * 16 + l15;
                af[i] = *(const bf16x8*)(As + (r << 6) + (((quad + cb) ^ l7) << 3));
            }
#pragma unroll
            for (int j = 0; j < 4; ++j) {
                int r = wn * 64 + j * 16 + l15;
                bfr[j] = *(const bf16x8*)(Bs + (r << 6) + (((quad + cb) ^ l7) << 3));
            }
#pragma unroll
            for (int i = 0; i < 4; ++i)
#pragma unroll
                for (int j = 0; j < 4; ++j)
                    acc[i][j] = __builtin_amdgcn_mfma_f32_16x16x32_bf16(
                        af[i], bfr[j], acc[i][j], 0, 0, 0);
        }
        __syncthreads();
    }

    // epilogue: C row = wm*64+i*16+quad*4+r, col(u) = n0+wn*64+j*16+l15
    const int b = m0 >> 11;
    const float* qp = qpb + b * U_;
    float qv[4], wv[4];
#pragma unroll
    for (int j = 0; j < 4; ++j) {
        int u = n0 + wn * 64 + j * 16 + l15;
        qv[j] = qp[u];
        wv[j] = Wv[u];
    }
#pragma unroll
    for (int i = 0; i < 4; ++i) {
#pragma unroll
        for (int r = 0; r < 4; ++r) {
            float s = 0.f;
#pragma unroll
            for (int j = 0; j < 4; ++j) s += fast_tanh(acc[i][j][r] + qv[j]) * wv[j];
            s += __shfl_xor(s, 1);
            s += __shfl_xor(s, 2);
            s += __shfl_xor(s, 4);
            s += __shfl_xor(s, 8);
            if (l15 == 0) atomicAdd(&sScore[wm * 64 + i * 16 + quad * 4 + r], s);
        }
    }
    __syncthreads();
    if (tid < BM) scores_partial[(size_t)(m0 + tid) * 8 + nt] = sScore[tid];
}

// ---------------- kernel 3: softmax over T per batch -----------------------
__global__ __launch_bounds__(256) void k_softmax(const float* __restrict__ scores_partial,
                                                 const float* __restrict__ bv,
                                                 float* __restrict__ out_w) {
    const int b = blockIdx.x;
    __shared__ float s[T_];
    __shared__ float red[4];
    const int tid = threadIdx.x;
    const float bvf = bv[0];

    float lmax = -1e30f;
    for (int t = tid; t < T_; t += 256) {
        const float* p = scores_partial + (size_t)(b * T_ + t) * 8;
        float sc = ((p[0] + p[1]) + (p[2] + p[3])) + ((p[4] + p[5]) + (p[6] + p[7])) + bvf;
        s[t] = sc;
        lmax = fmaxf(lmax, sc);
    }
    for (int off = 32; off; off >>= 1) lmax = fmaxf(lmax, __shfl_xor(lmax, off));
    if ((tid & 63) == 0) red[tid >> 6] = lmax;
    __syncthreads();
    const float gmax = fmaxf(fmaxf(red[0], red[1]), fmaxf(red[2], red[3]));

    float lsum = 0.f;
    for (int t = tid; t < T_; t += 256) {
        float e = __expf(s[t] - gmax);
        s[t] = e;
        lsum += e;
    }
    for (int off = 32; off; off >>= 1) lsum += __shfl_xor(lsum, off);
    __syncthreads();
    if ((tid & 63) == 0) red[tid >> 6] = lsum;
    __syncthreads();
    const float ginv = 1.f / ((red[0] + red[1]) + (red[2] + red[3]));

    for (int t = tid; t < T_; t += 256) out_w[b * T_ + t] = s[t] * ginv;
}

// -------- kernel 4: ctx partials (fp32, non-atomic), 64 rows/block ---------
__global__ __launch_bounds__(256) void k_ctx(const float* __restrict__ values,
                                             const float* __restrict__ out_w,
                                             float* __restrict__ ctx_part) {
    const int tc = blockIdx.x;  // 0..31
    const int b = blockIdx.y;   // 0..31
    const int tid = threadIdx.x;
    __shared__ float wls[64];
    if (tid < 64) wls[tid] = out_w[b * T_ + tc * 64 + tid];
    __syncthreads();

    f32x4 acc = (f32x4){0.f, 0.f, 0.f, 0.f};
    const float* base = values + (size_t)(b * T_ + tc * 64) * D_ + tid * 4;
#pragma unroll 4
    for (int tt = 0; tt < 64; ++tt)
        acc += wls[tt] * *(const f32x4*)(base + (size_t)tt * D_);
    *(f32x4*)(ctx_part + ((size_t)(tc * 32 + b) << 10) + tid * 4) = acc;
}

// -------- kernel 5: reduce 32 partials -> out_ctx --------------------------
__global__ __launch_bounds__(256) void k_ctx_fin(const float* __restrict__ ctx_part,
                                                 float* __restrict__ out_ctx) {
    const int b = blockIdx.x;  // 0..31
    const int tid = threadIdx.x;
    f32x4 s = (f32x4){0.f, 0.f, 0.f, 0.f};
#pragma unroll
    for (int tc = 0; tc < 32; ++tc)
        s += *(const f32x4*)(ctx_part + ((size_t)(tc * 32 + b) << 10) + tid * 4);
    *(f32x4*)(out_ctx + b * D_ + tid * 4) = s;
}

// ---------------------------------------------------------------------------
extern "C" void kernel_launch(void* const* d_in, const int* in_sizes, int n_in,
                              void* d_out, int out_size, void* d_ws, size_t ws_size,
                              hipStream_t stream) {
    const float* query  = (const float*)d_in[0];
    const float* values = (const float*)d_in[1];
    const float* W1     = (const float*)d_in[2];
    const float* b1     = (const float*)d_in[3];
    const float* W2     = (const float*)d_in[4];
    const float* b2     = (const float*)d_in[5];
    const float* Wv     = (const float*)d_in[6];
    const float* bv     = (const float*)d_in[7];

    float* out_ctx = (float*)d_out;          // [32*1024]
    float* out_w   = out_ctx + B_ * D_;      // [32*2048]

    char* ws = (char*)d_ws;
    // Footprint 0x500000 + 128 MB = 133.25 MB (r1-verified bound).
    // ctx_part (4 MB) ALIASES [0, 0x400000): W2T + qpb + most of sp.
    // Safe: W2T/qpb dead after k_score_gemm, sp dead after k_softmax; k_ctx
    // (which writes ctx_part) only starts after k_softmax in stream order,
    // and next iteration's k_prep rewrites W2T only after k_ctx_fin is done.
    const size_t OFF_W2T = 0;                 // 2 MB bf16
    const size_t OFF_QPB = 0x200000;          // 128 KB
    const size_t OFF_SP  = 0x220000;          // 2 MB
    const size_t OFF_VB  = 0x500000;          // 128 MB bf16 values

    ushort_t* W2T            = (ushort_t*)(ws + OFF_W2T);
    float*    ctx_part       = (float*)(ws + OFF_W2T);   // 4 MB alias, see above
    float*    qpb            = (float*)(ws + OFF_QPB);
    float*    scores_partial = (float*)(ws + OFF_SP);
    ushort_t* vb             = (ushort_t*)(ws + OFF_VB);

    k_prep<<<dim3(QPROJ_B + CONV_B + TRANS_B), 256, 0, stream>>>(
        W2, query, W1, b1, b2, values, W2T, qpb, vb);
    k_score_gemm<<<dim3((M_ / BM) * (U_ / BN)), 256, 0, stream>>>(
        vb, W2T, qpb, Wv, scores_partial);
    k_softmax<<<dim3(B_), 256, 0, stream>>>(scores_partial, bv, out_w);
    k_ctx<<<dim3(32, B_), 256, 0, stream>>>(values, out_w, ctx_part);
    k_ctx_fin<<<dim3(B_), 256, 0, stream>>>(ctx_part, out_ctx);

    (void)in_sizes; (void)n_in; (void)out_size; (void)ws_size;
}

// Round 10
// 600.773 us; speedup vs baseline: 1.1703x; 1.0462x over previous
//
#include <hip/hip_runtime.h>
#include <hip/hip_bf16.h>
#include <stdint.h>

// ---------------------------------------------------------------------------
// Bahdanau additive attention, B=32, T=2048, D=U=1024. fp32 in/out.
// Outputs (fp32, flat): ctx [32*1024] then weights [32*2048].
// Round 12: GEMM rebuilt on the 256x256 phase-interleaved schedule (8 waves,
// BK=64, 128 KB LDS dbuf, raw s_barrier + counted vmcnt + setprio around
// MFMA clusters). 4 phases per K-tile; next K-tile's 8 DMA loads issued in
// phases 0-1, drained by a single vmcnt(0) right before the K-tile boundary
// barrier (2-3 phases of latency hiding). Same 16B-chunk XOR swizzle (proven
// 0-conflict) on DMA source + LDS read. Tail kernels unchanged from r11.
// ---------------------------------------------------------------------------

typedef unsigned short ushort_t;
typedef short bf16x8 __attribute__((ext_vector_type(8)));
typedef float f32x4 __attribute__((ext_vector_type(4)));

#define GLOBAL_AS __attribute__((address_space(1)))
#define LDS_AS    __attribute__((address_space(3)))

__device__ __forceinline__ ushort_t f2bf(float f) {
    union { float f; unsigned int u; } v;
    v.f = f;
    unsigned int u = v.u;
    unsigned int r = u + 0x7FFFu + ((u >> 16) & 1u);  // RNE
    return (ushort_t)(r >> 16);
}
__device__ __forceinline__ unsigned int pk2(float a, float b) {
    union { __hip_bfloat162 h; unsigned int u; } c;
    c.h = __float22bfloat162_rn(make_float2(a, b));  // v_cvt_pk_bf16_f32
    return c.u;
}
__device__ __forceinline__ float fast_tanh(float x) {
    float ax = __builtin_fabsf(x);
    float e = __expf(-2.0f * ax);
    float t = (1.0f - e) * __builtin_amdgcn_rcpf(1.0f + e);
    return __builtin_copysignf(t, x);
}

static constexpr int B_ = 32, T_ = 2048, D_ = 1024, U_ = 1024;
static constexpr int M_ = B_ * T_;  // 65536
static constexpr int QPROJ_B = 64;   // (4 batch-groups of 8) x (16 u-chunks of 64)
static constexpr int CONV_B  = 4096; // values convert blocks
static constexpr int TRANS_B = 1024;

// ------ kernel 1: fused prep (qproj FIRST | convert | transpose LAST) ------
__global__ __launch_bounds__(256) void k_prep(const float* __restrict__ W2,
                                              const float* __restrict__ query,
                                              const float* __restrict__ W1,
                                              const float* __restrict__ b1,
                                              const float* __restrict__ b2,
                                              const float* __restrict__ values,
                                              ushort_t* __restrict__ W2T,
                                              float* __restrict__ qpb,
                                              ushort_t* __restrict__ vb) {
    __shared__ float smem[8192 + 4 * 64 * 9];  // qs[8][1024] | red[4][64][9(pad)]
    int bid = blockIdx.x;
    const int tid = threadIdx.x;

    if (bid < QPROJ_B) {
        // qproj: qpb[b][u] = query[b]@W1[:,u] + b1[u] + b2[u]  (8 batches/blk)
        const int bg = bid >> 4;  // batch group of 8
        const int uc = bid & 15;  // 64-u chunk

        float* qs = smem;  // [8][1024]
        float(*red)[64][9] = (float(*)[64][9])(smem + 8192);

        for (int i = tid; i < 8 * 1024; i += 256)
            qs[i] = query[(size_t)(bg * 8 + (i >> 10)) * D_ + (i & 1023)];
        __syncthreads();

        const int ul = tid & 63, ds = tid >> 6;
        const int u = uc * 64 + ul;
        float acc[8] = {0.f, 0.f, 0.f, 0.f, 0.f, 0.f, 0.f, 0.f};
#pragma unroll 8
        for (int d = ds * 256; d < ds * 256 + 256; ++d) {
            const float w = W1[(size_t)d * U_ + u];
#pragma unroll
            for (int b = 0; b < 8; ++b) acc[b] += qs[(b << 10) + d] * w;
        }
#pragma unroll
        for (int b = 0; b < 8; ++b) red[ds][ul][b] = acc[b];
        __syncthreads();
        for (int i = tid; i < 512; i += 256) {
            const int b = i & 7, uu = i >> 3;
            const float s =
                (red[0][uu][b] + red[1][uu][b]) + (red[2][uu][b] + red[3][uu][b]);
            const int ug = uc * 64 + uu;
            qpb[(size_t)(bg * 8 + b) * U_ + ug] = s + b1[ug] + b2[ug];
        }
        return;
    }
    bid -= QPROJ_B;

    if (bid < CONV_B) {  // values fp32 -> bf16
        const size_t base = (size_t)bid * 2048 + tid;
#pragma unroll
        for (int k = 0; k < 8; ++k) {
            const size_t chunk = base + (size_t)k * 256;  // 8 floats per chunk
            const float* s = values + chunk * 8;
            f32x4 v0 = *(const f32x4*)s;
            f32x4 v1 = *(const f32x4*)(s + 4);
            uint4 p;
            p.x = pk2(v0[0], v0[1]);
            p.y = pk2(v0[2], v0[3]);
            p.z = pk2(v1[0], v1[1]);
            p.w = pk2(v1[2], v1[3]);
            *(uint4*)(vb + chunk * 8) = p;
        }
        return;
    }
    bid -= CONV_B;

    // W2 [D][U] -> W2T [U][D] bf16
    {
        float(*tile)[33] = (float(*)[33])smem;
        int u0 = (bid & 31) * 32, d0 = (bid >> 5) * 32;
        int tx = tid & 31, ty = tid >> 5;
#pragma unroll
        for (int r = 0; r < 4; ++r)
            tile[ty + r * 8][tx] = W2[(size_t)(d0 + ty + r * 8) * U_ + (u0 + tx)];
        __syncthreads();
#pragma unroll
        for (int r = 0; r < 4; ++r)
            W2T[(size_t)(u0 + ty + r * 8) * D_ + (d0 + tx)] = f2bf(tile[tx][ty + r * 8]);
    }
}

// ---------------- kernel 2: fused GEMM + tanh + Wv-dot ---------------------
// 256x256 tile, 8 waves (2Mx4N), BK=64, double-buffered 128 KB LDS, DMA
// staging with source-side 16B-chunk XOR swizzle (LDS chunk p of row r holds
// source chunk p^(r&7)); 4 phases per K-tile, raw barriers, counted vmcnt.
#define BM2 256
#define BN2 256
#define BK2 64
#define NKT 16  // D_/BK2

__global__ __launch_bounds__(512) void k_score_gemm(const ushort_t* __restrict__ vb,
                                                    const ushort_t* __restrict__ W2T,
                                                    const float* __restrict__ qpb,
                                                    const float* __restrict__ Wv,
                                                    float* __restrict__ scores_partial) {
    __shared__ ushort_t As[2][BM2 * BK2];  // 2 x 32 KB
    __shared__ ushort_t Bs[2][BN2 * BK2];  // 2 x 32 KB
    __shared__ float sScore[BM2];

    const int tid = threadIdx.x;
    const int lane = tid & 63;
    const int w = tid >> 6;   // 0..7
    const int wm = w >> 2;    // 0..1  -> 128-row strip
    const int wn = w & 3;     // 0..3  -> 64-col strip

    const int g = blockIdx.x;                    // 1024 blocks
    const int mt = ((g >> 5) << 3) | (g & 7);    // XCD-grouped, bijective
    const int nt = (g >> 3) & 3;
    const int m0 = mt * BM2, n0 = nt * BN2;

    if (tid < BM2) sScore[tid] = 0.f;

    f32x4 acc[8][4];
#pragma unroll
    for (int i = 0; i < 8; ++i)
#pragma unroll
        for (int j = 0; j < 4; ++j) acc[i][j] = (f32x4){0.f, 0.f, 0.f, 0.f};

    // ---- DMA staging map: instr i covers rows i*64 + w*8 + (lane>>3) ----
    const int sr = lane >> 3;         // 0..7
    const int cS = (lane & 7) ^ sr;   // pre-swizzled source chunk
    const ushort_t* aSrc = vb + (size_t)(m0 + w * 8 + sr) * D_ + cS * 8;
    const ushort_t* bSrc = W2T + (size_t)(n0 + w * 8 + sr) * D_ + cS * 8;

    const int quad = lane >> 4, l15 = lane & 15, l7 = l15 & 7;

#define GLD(S, Dbase, i)                                               \
    __builtin_amdgcn_global_load_lds(                                  \
        (const GLOBAL_AS void*)((S) + (size_t)(i) * 64 * D_),          \
        (LDS_AS void*)((Dbase) + (i) * 4096 + w * 512), 16, 0, 0)

// fragment reads (16B-chunk XOR unswizzle on read)
#define RD_A(dst, r16, kc, BUF)                                        \
    dst = *(const bf16x8*)((BUF) + ((wm * 128 + (r16) * 16 + l15) << 6) + \
                           (((quad + (kc) * 4) ^ l7) << 3))
#define RD_B(dst, nj, kc, BUF)                                         \
    dst = *(const bf16x8*)((BUF) + ((wn * 64 + (nj) * 16 + l15) << 6) + \
                           (((quad + (kc) * 4) ^ l7) << 3))

#define MFMA_Q(Mh, Nh, BF)                                             \
    do {                                                               \
        _Pragma("unroll") for (int mi = 0; mi < 4; ++mi) {             \
            _Pragma("unroll") for (int njl = 0; njl < 2; ++njl) {      \
                acc[(Mh)*4 + mi][(Nh)*2 + njl] =                       \
                    __builtin_amdgcn_mfma_f32_16x16x32_bf16(           \
                        aF[mi * 2 + 0], BF[njl * 2 + 0],               \
                        acc[(Mh)*4 + mi][(Nh)*2 + njl], 0, 0, 0);      \
                acc[(Mh)*4 + mi][(Nh)*2 + njl] =                       \
                    __builtin_amdgcn_mfma_f32_16x16x32_bf16(           \
                        aF[mi * 2 + 1], BF[njl * 2 + 1],               \
                        acc[(Mh)*4 + mi][(Nh)*2 + njl], 0, 0, 0);      \
            }                                                          \
        }                                                              \
    } while (0)

    // prologue: stage K-tile 0 into buf 0, full drain
#pragma unroll
    for (int i = 0; i < 4; ++i) GLD(aSrc, As[0], i);
#pragma unroll
    for (int i = 0; i < 4; ++i) GLD(bSrc, Bs[0], i);
    __syncthreads();  // vmcnt(0)+lgkmcnt(0)+barrier: kt0 resident, sScore init

    bf16x8 aF[8], bF0[4], bF1[4];

    for (int kt = 0; kt < NKT - 1; ++kt) {
        const ushort_t* Ac = As[kt & 1];
        const ushort_t* Bc = Bs[kt & 1];
        ushort_t* An = (ushort_t*)As[(kt + 1) & 1];
        ushort_t* Bn = (ushort_t*)Bs[(kt + 1) & 1];
        const ushort_t* aS = aSrc + (size_t)(kt + 1) * BK2;
        const ushort_t* bS = bSrc + (size_t)(kt + 1) * BK2;

        // ---- phase 0: A-half0 + B-lo frags | stage A01,B01 | MFMA (0,0)
        RD_A(aF[0], 0, 0, Ac); RD_A(aF[1], 0, 1, Ac);
        RD_A(aF[2], 1, 0, Ac); RD_A(aF[3], 1, 1, Ac);
        RD_A(aF[4], 2, 0, Ac); RD_A(aF[5], 2, 1, Ac);
        RD_A(aF[6], 3, 0, Ac); RD_A(aF[7], 3, 1, Ac);
        RD_B(bF0[0], 0, 0, Bc); RD_B(bF0[1], 0, 1, Bc);
        RD_B(bF0[2], 1, 0, Bc); RD_B(bF0[3], 1, 1, Bc);
        GLD(aS, An, 0); GLD(aS, An, 1);
        GLD(bS, Bn, 0); GLD(bS, Bn, 1);
        __builtin_amdgcn_s_barrier();
        __builtin_amdgcn_s_setprio(1);
        MFMA_Q(0, 0, bF0);
        __builtin_amdgcn_s_setprio(0);
        __builtin_amdgcn_s_barrier();

        // ---- phase 1: B-hi frags | stage A23,B23 | MFMA (0,1)
        RD_B(bF1[0], 2, 0, Bc); RD_B(bF1[1], 2, 1, Bc);
        RD_B(bF1[2], 3, 0, Bc); RD_B(bF1[3], 3, 1, Bc);
        GLD(aS, An, 2); GLD(aS, An, 3);
        GLD(bS, Bn, 2); GLD(bS, Bn, 3);
        __builtin_amdgcn_s_barrier();
        __builtin_amdgcn_s_setprio(1);
        MFMA_Q(0, 1, bF1);
        __builtin_amdgcn_s_setprio(0);
        __builtin_amdgcn_s_barrier();

        // ---- phase 2: A-half1 frags | MFMA (1,0)
        RD_A(aF[0], 4, 0, Ac); RD_A(aF[1], 4, 1, Ac);
        RD_A(aF[2], 5, 0, Ac); RD_A(aF[3], 5, 1, Ac);
        RD_A(aF[4], 6, 0, Ac); RD_A(aF[5], 6, 1, Ac);
        RD_A(aF[6], 7, 0, Ac); RD_A(aF[7], 7, 1, Ac);
        __builtin_amdgcn_s_barrier();
        __builtin_amdgcn_s_setprio(1);
        MFMA_Q(1, 0, bF0);
        __builtin_amdgcn_s_setprio(0);
        __builtin_amdgcn_s_barrier();

        // ---- phase 3: MFMA (1,1) | counted drain of kt+1's 8 loads
        __builtin_amdgcn_s_setprio(1);
        MFMA_Q(1, 1, bF1);
        __builtin_amdgcn_s_setprio(0);
        asm volatile("s_waitcnt vmcnt(0)" ::: "memory");
        __builtin_amdgcn_sched_barrier(0);
        __builtin_amdgcn_s_barrier();
    }

    // ---- tail K-tile (buf 1, fully resident; no staging, no barriers)
    {
        const ushort_t* Ac = As[(NKT - 1) & 1];
        const ushort_t* Bc = Bs[(NKT - 1) & 1];
        RD_A(aF[0], 0, 0, Ac); RD_A(aF[1], 0, 1, Ac);
        RD_A(aF[2], 1, 0, Ac); RD_A(aF[3], 1, 1, Ac);
        RD_A(aF[4], 2, 0, Ac); RD_A(aF[5], 2, 1, Ac);
        RD_A(aF[6], 3, 0, Ac); RD_A(aF[7], 3, 1, Ac);
        RD_B(bF0[0], 0, 0, Bc); RD_B(bF0[1], 0, 1, Bc);
        RD_B(bF0[2], 1, 0, Bc); RD_B(bF0[3], 1, 1, Bc);
        RD_B(bF1[0], 2, 0, Bc); RD_B(bF1[1], 2, 1, Bc);
        RD_B(bF1[2], 3, 0, Bc); RD_B(bF1[3], 3, 1, Bc);
        MFMA_Q(0, 0, bF0);
        MFMA_Q(0, 1, bF1);
        RD_A(aF[0], 4, 0, Ac); RD_A(aF[1], 4, 1, Ac);
        RD_A(aF[2], 5, 0, Ac); RD_A(aF[3], 5, 1, Ac);
        RD_A(aF[4], 6, 0, Ac); RD_A(aF[5], 6, 1, Ac);
        RD_A(aF[6], 7, 0, Ac); RD_A(aF[7], 7, 1, Ac);
        MFMA_Q(1, 0, bF0);
        MFMA_Q(1, 1, bF1);
    }

    // epilogue: C row = wm*128 + Mi*16 + quad*4 + r, col = n0 + wn*64 + nj*16 + l15
    const int b = m0 >> 11;
    const float* qp = qpb + b * U_;
    float qv[4], wv[4];
#pragma unroll
    for (int nj = 0; nj < 4; ++nj) {
        int u = n0 + wn * 64 + nj * 16 + l15;
        qv[nj] = qp[u];
        wv[nj] = Wv[u];
    }
#pragma unroll
    for (int Mi = 0; Mi < 8; ++Mi) {
#pragma unroll
        for (int r = 0; r < 4; ++r) {
            float s = 0.f;
#pragma unroll
            for (int nj = 0; nj < 4; ++nj)
                s += fast_tanh(acc[Mi][nj][r] + qv[nj]) * wv[nj];
            s += __shfl_xor(s, 1);
            s += __shfl_xor(s, 2);
            s += __shfl_xor(s, 4);
            s += __shfl_xor(s, 8);
            if (l15 == 0)
                atomicAdd(&sScore[wm * 128 + Mi * 16 + quad * 4 + r], s);
        }
    }
    __syncthreads();
    if (tid < BM2) scores_partial[(size_t)(m0 + tid) * 4 + nt] = sScore[tid];
#undef GLD
#undef RD_A
#undef RD_B
#undef MFMA_Q
}

// ---------------- kernel 3: softmax over T per batch -----------------------
__global__ __launch_bounds__(256) void k_softmax(const float* __restrict__ scores_partial,
                                                 const float* __restrict__ bv,
                                                 float* __restrict__ out_w) {
    const int b = blockIdx.x;
    __shared__ float s[T_];
    __shared__ float red[4];
    const int tid = threadIdx.x;
    const float bvf = bv[0];

    float lmax = -1e30f;
    for (int t = tid; t < T_; t += 256) {
        const float* p = scores_partial + (size_t)(b * T_ + t) * 4;
        float sc = (p[0] + p[1]) + (p[2] + p[3]) + bvf;
        s[t] = sc;
        lmax = fmaxf(lmax, sc);
    }
    for (int off = 32; off; off >>= 1) lmax = fmaxf(lmax, __shfl_xor(lmax, off));
    if ((tid & 63) == 0) red[tid >> 6] = lmax;
    __syncthreads();
    const float gmax = fmaxf(fmaxf(red[0], red[1]), fmaxf(red[2], red[3]));

    float lsum = 0.f;
    for (int t = tid; t < T_; t += 256) {
        float e = __expf(s[t] - gmax);
        s[t] = e;
        lsum += e;
    }
    for (int off = 32; off; off >>= 1) lsum += __shfl_xor(lsum, off);
    __syncthreads();
    if ((tid & 63) == 0) red[tid >> 6] = lsum;
    __syncthreads();
    const float ginv = 1.f / ((red[0] + red[1]) + (red[2] + red[3]));

    for (int t = tid; t < T_; t += 256) out_w[b * T_ + t] = s[t] * ginv;
}

// -------- kernel 4: ctx partials (fp32, non-atomic), 64 rows/block ---------
__global__ __launch_bounds__(256) void k_ctx(const float* __restrict__ values,
                                             const float* __restrict__ out_w,
                                             float* __restrict__ ctx_part) {
    const int tc = blockIdx.x;  // 0..31
    const int b = blockIdx.y;   // 0..31
    const int tid = threadIdx.x;
    __shared__ float wls[64];
    if (tid < 64) wls[tid] = out_w[b * T_ + tc * 64 + tid];
    __syncthreads();

    f32x4 acc = (f32x4){0.f, 0.f, 0.f, 0.f};
    const float* base = values + (size_t)(b * T_ + tc * 64) * D_ + tid * 4;
#pragma unroll 4
    for (int tt = 0; tt < 64; ++tt)
        acc += wls[tt] * *(const f32x4*)(base + (size_t)tt * D_);
    *(f32x4*)(ctx_part + ((size_t)(tc * 32 + b) << 10) + tid * 4) = acc;
}

// -------- kernel 5: reduce 32 partials -> out_ctx --------------------------
__global__ __launch_bounds__(256) void k_ctx_fin(const float* __restrict__ ctx_part,
                                                 float* __restrict__ out_ctx) {
    const int b = blockIdx.x;  // 0..31
    const int tid = threadIdx.x;
    f32x4 s = (f32x4){0.f, 0.f, 0.f, 0.f};
#pragma unroll
    for (int tc = 0; tc < 32; ++tc)
        s += *(const f32x4*)(ctx_part + ((size_t)(tc * 32 + b) << 10) + tid * 4);
    *(f32x4*)(out_ctx + b * D_ + tid * 4) = s;
}

// ---------------------------------------------------------------------------
extern "C" void kernel_launch(void* const* d_in, const int* in_sizes, int n_in,
                              void* d_out, int out_size, void* d_ws, size_t ws_size,
                              hipStream_t stream) {
    const float* query  = (const float*)d_in[0];
    const float* values = (const float*)d_in[1];
    const float* W1     = (const float*)d_in[2];
    const float* b1     = (const float*)d_in[3];
    const float* W2     = (const float*)d_in[4];
    const float* b2     = (const float*)d_in[5];
    const float* Wv     = (const float*)d_in[6];
    const float* bv     = (const float*)d_in[7];

    float* out_ctx = (float*)d_out;          // [32*1024]
    float* out_w   = out_ctx + B_ * D_;      // [32*2048]

    char* ws = (char*)d_ws;
    // Footprint 0x500000 + 128 MB = 133.25 MB (r1-verified bound).
    // ctx_part (4 MB) ALIASES [0, 0x400000): W2T + qpb + part of sp.
    // Safe: W2T/qpb dead after k_score_gemm, sp dead after k_softmax; k_ctx
    // only starts after k_softmax; next iteration's k_prep rewrites W2T after
    // k_ctx_fin completes (stream order).
    const size_t OFF_W2T = 0;                 // 2 MB bf16
    const size_t OFF_QPB = 0x200000;          // 128 KB
    const size_t OFF_SP  = 0x220000;          // 1 MB used (2 MB reserved)
    const size_t OFF_VB  = 0x500000;          // 128 MB bf16 values

    ushort_t* W2T            = (ushort_t*)(ws + OFF_W2T);
    float*    ctx_part       = (float*)(ws + OFF_W2T);   // 4 MB alias, see above
    float*    qpb            = (float*)(ws + OFF_QPB);
    float*    scores_partial = (float*)(ws + OFF_SP);
    ushort_t* vb             = (ushort_t*)(ws + OFF_VB);

    k_prep<<<dim3(QPROJ_B + CONV_B + TRANS_B), 256, 0, stream>>>(
        W2, query, W1, b1, b2, values, W2T, qpb, vb);
    k_score_gemm<<<dim3((M_ / BM2) * (U_ / BN2)), 512, 0, stream>>>(
        vb, W2T, qpb, Wv, scores_partial);
    k_softmax<<<dim3(B_), 256, 0, stream>>>(scores_partial, bv, out_w);
    k_ctx<<<dim3(32, B_), 256, 0, stream>>>(values, out_w, ctx_part);
    k_ctx_fin<<<dim3(B_), 256, 0, stream>>>(ctx_part, out_ctx);

    (void)in_sizes; (void)n_in; (void)out_size; (void)ws_size;
}